// Round 2
// baseline (4748.436 us; speedup 1.0000x reference)
//
#include <hip/hip_runtime.h>
#include <hip/hip_bf16.h>

#define Bb 32
#define Tt 512
#define Ii 256
#define Hh 512
#define Oo 128
#define NG 32   // workgroups per direction in recurrence

using bf16x8 = __attribute__((ext_vector_type(8))) __bf16;
using f32x4  = __attribute__((ext_vector_type(4))) float;

__device__ __forceinline__ bf16x8 f32x8_to_bf16(const float* p) {
    const float4 u = *reinterpret_cast<const float4*>(p);
    const float4 v = *reinterpret_cast<const float4*>(p + 4);
    bf16x8 r;
    r[0] = (__bf16)u.x; r[1] = (__bf16)u.y; r[2] = (__bf16)u.z; r[3] = (__bf16)u.w;
    r[4] = (__bf16)v.x; r[5] = (__bf16)v.y; r[6] = (__bf16)v.z; r[7] = (__bf16)v.w;
    return r;
}

// ---------------- setup: zero counters, build initial h (fwd=0, bwd=bh0) ----
__global__ void k_setup(const float* __restrict__ bh0,
                        __bf16* __restrict__ hinit, int* __restrict__ cnt) {
    const int tid = blockIdx.x * 256 + threadIdx.x;
    if (tid < 32) cnt[tid] = 0;
    if (tid < Bb * Hh) {
        hinit[tid] = (__bf16)0.f;
        hinit[Bb * Hh + tid] = (__bf16)bh0[tid & (Hh - 1)];
    }
}

// ---------------- xproj = x @ Wx^T + b  -> [T][B][4H] bf16 -------------------
__global__ __launch_bounds__(256) void k_xproj(
    const float* __restrict__ x,
    const float* __restrict__ Wf, const float* __restrict__ bf_,
    const float* __restrict__ Wi, const float* __restrict__ bi_,
    const float* __restrict__ Wo, const float* __restrict__ bo_,
    const float* __restrict__ Wc, const float* __restrict__ bc_,
    __bf16* __restrict__ xproj)
{
    const int wgM = blockIdx.x;           // 0..255  (64 rows each)
    const int wgN = blockIdx.y;           // 0..15   (128 cols each)
    const int tid = threadIdx.x;
    const int wave = tid >> 6, lane = tid & 63;
    const int mw = wave >> 1, nw = wave & 1;
    const int l15 = lane & 15, lhi = lane >> 4;

    const int gamma = wgN >> 2;           // whole wg in one gate (128 | 512)
    const float* W    = (gamma == 0) ? Wf : (gamma == 1) ? Wi : (gamma == 2) ? Wo : Wc;
    const float* bptr = (gamma == 0) ? bf_ : (gamma == 1) ? bi_ : (gamma == 2) ? bo_ : bc_;

    f32x4 acc[2][4];
#pragma unroll
    for (int m = 0; m < 2; m++)
#pragma unroll
        for (int n = 0; n < 4; n++) acc[m][n] = f32x4{0.f, 0.f, 0.f, 0.f};

    const int rowbase = wgM * 64 + mw * 32;
    const int colbase = wgN * 128 + nw * 64;

#pragma unroll
    for (int kk = 0; kk < 8; ++kk) {
        const int k0 = kk * 32 + lhi * 8;
        bf16x8 a[2], b[4];
#pragma unroll
        for (int m = 0; m < 2; m++) {
            const int r = rowbase + m * 16 + l15;        // x row = b*T + t
            a[m] = f32x8_to_bf16(x + (long)r * Ii + k0);
        }
#pragma unroll
        for (int n = 0; n < 4; n++) {
            const int g = colbase + n * 16 + l15;
            b[n] = f32x8_to_bf16(W + (long)(g & 511) * 768 + k0);
        }
#pragma unroll
        for (int m = 0; m < 2; m++)
#pragma unroll
            for (int n = 0; n < 4; n++)
                acc[m][n] = __builtin_amdgcn_mfma_f32_16x16x32_bf16(a[m], b[n], acc[m][n], 0, 0, 0);
    }

#pragma unroll
    for (int m = 0; m < 2; m++)
#pragma unroll
        for (int n = 0; n < 4; n++) {
            const int g = colbase + n * 16 + l15;
            const float bias = bptr[g & 511];
#pragma unroll
            for (int r = 0; r < 4; r++) {
                const int R = rowbase + m * 16 + lhi * 4 + r;   // = b*T + t
                const int t = R & (Tt - 1), bb = R >> 9;
                xproj[((long)t * Bb + bb) * 2048 + g] = (__bf16)(acc[m][n][r] + bias);
            }
        }
}

// ---------------- recurrence: 2 dirs x NG wgs, manual per-step barrier -------
__global__ __launch_bounds__(256) void k_rec(
    const float* __restrict__ Wf, const float* __restrict__ Wi,
    const float* __restrict__ Wo, const float* __restrict__ Wc,
    const float* __restrict__ bc0,
    const __bf16* __restrict__ xproj,
    __bf16* __restrict__ hs,           // [2][T][B][H]
    const __bf16* __restrict__ hinit,  // [2][B][H]
    int* cnt)
{
    const int dir  = blockIdx.x >> 5;
    const int gsel = blockIdx.x & 31;       // owns h-cols [gsel*16, gsel*16+16)
    const int tid  = threadIdx.x;
    const int wave = tid >> 6;              // == gate index (f,i,o,c)
    const int lane = tid & 63;
    const int l15  = lane & 15, lhi = lane >> 4;

    __shared__ __bf16 hlds[32 * 512];       // swizzled h_{t-1}
    __shared__ float  gbuf[32][65];         // recurrent gate contributions

    // persistent B fragments: wave w holds gate w, cols gsel*16..+16 of Wh
    const float* Wp = (wave == 0) ? Wf : (wave == 1) ? Wi : (wave == 2) ? Wo : Wc;
    const float* wrow = Wp + (long)(gsel * 16 + l15) * 768 + Ii;   // recurrent part
    bf16x8 bfrag[16];
#pragma unroll
    for (int kk = 0; kk < 16; ++kk) bfrag[kk] = f32x8_to_bf16(wrow + kk * 32 + lhi * 8);

    // elementwise ownership: 2 (b,hc) pairs per thread
    const int b_ew = tid & 31;
    const int hcl0 = tid >> 5;              // 0..7
    const int hcl1 = hcl0 + 8;              // 8..15
    float c0s = (dir == 0) ? 0.f : bc0[gsel * 16 + hcl0];
    float c1s = (dir == 0) ? 0.f : bc0[gsel * 16 + hcl1];

    int* counter = cnt + dir * 16;
    __bf16* hsd = hs + (long)dir * Tt * Bb * Hh;

    for (int s = 0; s < Tt; ++s) {
        const int t = (dir == 0) ? s : (Tt - 1 - s);

        // prefetch this step's xproj gates (independent of the barrier)
        const __bf16* xp = xproj + ((long)t * Bb + b_ew) * 2048;
        float x0[4], x1[4];
#pragma unroll
        for (int g = 0; g < 4; ++g) {
            x0[g] = (float)xp[g * 512 + gsel * 16 + hcl0];
            x1[g] = (float)xp[g * 512 + gsel * 16 + hcl1];
        }

        if (s > 0) {
            if (tid == 0) {
                const int target = s * NG;
                // bounded spin: a broken barrier degrades to wrong results,
                // never a watchdog kill (diagnosability > purity)
                for (int p = 0; p < (1 << 18); ++p) {
                    if (__hip_atomic_load(counter, __ATOMIC_RELAXED,
                                          __HIP_MEMORY_SCOPE_AGENT) >= target) break;
                    __builtin_amdgcn_s_sleep(1);
                }
                __threadfence();   // acquire: invalidate L1/L2 so h reads are fresh
            }
        }
        __syncthreads();

        // stage h_{s-1} -> LDS with 16B XOR swizzle
        const __bf16* hp = (s == 0) ? (hinit + (long)dir * Bb * Hh)
                                    : (hsd + (long)((dir == 0) ? (t - 1) : (t + 1)) * Bb * Hh);
#pragma unroll
        for (int j = 0; j < 8; ++j) {
            const int lin = j * 256 + tid;      // 16B-chunk id, 0..2047
            const int r = lin >> 6, ck = lin & 63;
            const int byteoff = r * 1024 + ((ck * 16) ^ ((r & 7) << 4));
            *reinterpret_cast<bf16x8*>(reinterpret_cast<char*>(hlds) + byteoff) =
                *reinterpret_cast<const bf16x8*>(hp + (long)r * Hh + ck * 8);
        }
        __syncthreads();

        // this wave's gate: [32 x 512] @ [512 x 16]
        f32x4 acc0 = f32x4{0.f, 0.f, 0.f, 0.f};
        f32x4 acc1 = f32x4{0.f, 0.f, 0.f, 0.f};
#pragma unroll
        for (int kk = 0; kk < 16; ++kk) {
            const int kb = kk * 64 + lhi * 16;
            const int r0 = l15, r1 = 16 + l15;
            bf16x8 a0 = *reinterpret_cast<const bf16x8*>(
                reinterpret_cast<const char*>(hlds) + r0 * 1024 + (kb ^ ((r0 & 7) << 4)));
            bf16x8 a1 = *reinterpret_cast<const bf16x8*>(
                reinterpret_cast<const char*>(hlds) + r1 * 1024 + (kb ^ ((r1 & 7) << 4)));
            acc0 = __builtin_amdgcn_mfma_f32_16x16x32_bf16(a0, bfrag[kk], acc0, 0, 0, 0);
            acc1 = __builtin_amdgcn_mfma_f32_16x16x32_bf16(a1, bfrag[kk], acc1, 0, 0, 0);
        }
#pragma unroll
        for (int r = 0; r < 4; ++r) {
            gbuf[lhi * 4 + r][wave * 16 + l15]      = acc0[r];
            gbuf[16 + lhi * 4 + r][wave * 16 + l15] = acc1[r];
        }
        __syncthreads();

        // elementwise LSTM cell for 2 (b,hc) pairs
        float h0, h1;
        {
            const float gf = x0[0] + gbuf[b_ew][hcl0];
            const float gi = x0[1] + gbuf[b_ew][16 + hcl0];
            const float go = x0[2] + gbuf[b_ew][32 + hcl0];
            const float gc = x0[3] + gbuf[b_ew][48 + hcl0];
            const float f  = 1.f / (1.f + __expf(-gf));
            const float ii = 1.f / (1.f + __expf(-gi));
            const float oo = 1.f / (1.f + __expf(-go));
            c0s = f * c0s + ii * tanhf(gc);
            h0 = oo * tanhf(c0s);
        }
        {
            const float gf = x1[0] + gbuf[b_ew][hcl1];
            const float gi = x1[1] + gbuf[b_ew][16 + hcl1];
            const float go = x1[2] + gbuf[b_ew][32 + hcl1];
            const float gc = x1[3] + gbuf[b_ew][48 + hcl1];
            const float f  = 1.f / (1.f + __expf(-gf));
            const float ii = 1.f / (1.f + __expf(-gi));
            const float oo = 1.f / (1.f + __expf(-go));
            c1s = f * c1s + ii * tanhf(gc);
            h1 = oo * tanhf(c1s);
        }
        __bf16* hrow = hsd + ((long)t * Bb + b_ew) * Hh + gsel * 16;
        hrow[hcl0] = (__bf16)h0;
        hrow[hcl1] = (__bf16)h1;

        __syncthreads();   // all h stores drained (vmcnt(0) before barrier)
        if (tid == 0)
            __hip_atomic_fetch_add(counter, 1, __ATOMIC_RELEASE, __HIP_MEMORY_SCOPE_AGENT);
    }
}

// ---------------- out = cat(hf,hb) @ out_w^T + out_b -> [B][T][O] fp32 -------
__global__ __launch_bounds__(256) void k_out(
    const __bf16* __restrict__ hs,
    const float* __restrict__ out_w,
    const float* __restrict__ out_b,
    float* __restrict__ out)
{
    const int wgM = blockIdx.x;            // 0..255 (64 hs-rows each)
    const int tid = threadIdx.x;
    const int wave = tid >> 6, lane = tid & 63;
    const int mw = wave >> 1, nw = wave & 1;
    const int l15 = lane & 15, lhi = lane >> 4;

    f32x4 acc[2][4];
#pragma unroll
    for (int m = 0; m < 2; m++)
#pragma unroll
        for (int n = 0; n < 4; n++) acc[m][n] = f32x4{0.f, 0.f, 0.f, 0.f};

    const int rowbase = wgM * 64 + mw * 32;   // hs row = t*B + b
    const int colbase = nw * 64;

#pragma unroll 4
    for (int kk = 0; kk < 32; ++kk) {
        const int k0 = kk * 32 + lhi * 8;     // 0..1023
        const int d = k0 >> 9, hk = k0 & 511;
        bf16x8 a[2], b[4];
#pragma unroll
        for (int m = 0; m < 2; m++) {
            const int R = rowbase + m * 16 + l15;
            a[m] = *reinterpret_cast<const bf16x8*>(hs + ((long)d * 16384 + R) * 512 + hk);
        }
#pragma unroll
        for (int n = 0; n < 4; n++) {
            const int o = colbase + n * 16 + l15;
            b[n] = f32x8_to_bf16(out_w + (long)o * 1024 + k0);
        }
#pragma unroll
        for (int m = 0; m < 2; m++)
#pragma unroll
            for (int n = 0; n < 4; n++)
                acc[m][n] = __builtin_amdgcn_mfma_f32_16x16x32_bf16(a[m], b[n], acc[m][n], 0, 0, 0);
    }

#pragma unroll
    for (int m = 0; m < 2; m++)
#pragma unroll
        for (int n = 0; n < 4; n++) {
            const int o = colbase + n * 16 + l15;
            const float bias = out_b[o];
#pragma unroll
            for (int r = 0; r < 4; r++) {
                const int R = rowbase + m * 16 + lhi * 4 + r;   // t*32 + b
                const int tt = R >> 5, bb = R & 31;
                out[((long)bb * Tt + tt) * Oo + o] = acc[m][n][r] + bias;
            }
        }
}

// ---------------- launcher ---------------------------------------------------
extern "C" void kernel_launch(void* const* d_in, const int* in_sizes, int n_in,
                              void* d_out, int out_size, void* d_ws, size_t ws_size,
                              hipStream_t stream) {
    (void)in_sizes; (void)n_in; (void)out_size; (void)ws_size;
    const float* x    = (const float*)d_in[0];
    const float* Wf_w = (const float*)d_in[1];
    const float* Wf_b = (const float*)d_in[2];
    const float* Wi_w = (const float*)d_in[3];
    const float* Wi_b = (const float*)d_in[4];
    const float* Wo_w = (const float*)d_in[5];
    const float* Wo_b = (const float*)d_in[6];
    const float* Wc_w = (const float*)d_in[7];
    const float* Wc_b = (const float*)d_in[8];
    const float* out_w = (const float*)d_in[9];
    const float* out_b = (const float*)d_in[10];
    const float* bh0  = (const float*)d_in[11];
    const float* bc0  = (const float*)d_in[12];

    char* ws = (char*)d_ws;
    __bf16* xproj = (__bf16*)(ws);                       // 67108864 B
    __bf16* hs    = (__bf16*)(ws + 67108864);            // 33554432 B
    __bf16* hinit = (__bf16*)(ws + 100663296);           // 65536 B
    int*    cnt   = (int*)   (ws + 100728832);           // 128 B

    k_setup<<<64, 256, 0, stream>>>(bh0, hinit, cnt);
    dim3 g1(256, 16);
    k_xproj<<<g1, 256, 0, stream>>>(x, Wf_w, Wf_b, Wi_w, Wi_b, Wo_w, Wo_b, Wc_w, Wc_b, xproj);
    k_rec<<<2 * NG, 256, 0, stream>>>(Wf_w, Wi_w, Wo_w, Wc_w, bc0, xproj, hs, hinit, cnt);
    k_out<<<256, 256, 0, stream>>>(hs, out_w, out_b, (float*)d_out);
}

// Round 3
// 2263.174 us; speedup vs baseline: 2.0981x; 2.0981x over previous
//
#include <hip/hip_runtime.h>
#include <hip/hip_bf16.h>

#define Bb 32
#define Tt 512
#define Ii 256
#define Hh 512
#define Oo 128
#define NG 32   // workgroups per direction in recurrence

using bf16x8 = __attribute__((ext_vector_type(8))) __bf16;
using f32x4  = __attribute__((ext_vector_type(4))) float;

__device__ __forceinline__ bf16x8 f32x8_to_bf16(const float* p) {
    const float4 u = *reinterpret_cast<const float4*>(p);
    const float4 v = *reinterpret_cast<const float4*>(p + 4);
    bf16x8 r;
    r[0] = (__bf16)u.x; r[1] = (__bf16)u.y; r[2] = (__bf16)u.z; r[3] = (__bf16)u.w;
    r[4] = (__bf16)v.x; r[5] = (__bf16)v.y; r[6] = (__bf16)v.z; r[7] = (__bf16)v.w;
    return r;
}

// ---------------- setup: zero flags, build initial h (fwd=0, bwd=bh0) -------
__global__ void k_setup(const float* __restrict__ bh0,
                        __bf16* __restrict__ hinit, int* __restrict__ flags) {
    const int tid = blockIdx.x * 256 + threadIdx.x;
    if (tid < 64) flags[tid] = 0;
    if (tid < Bb * Hh) {
        hinit[tid] = (__bf16)0.f;
        hinit[Bb * Hh + tid] = (__bf16)bh0[tid & (Hh - 1)];
    }
}

// ---------------- xproj = x @ Wx^T + b  -> [T][B][4H] bf16 -------------------
__global__ __launch_bounds__(256) void k_xproj(
    const float* __restrict__ x,
    const float* __restrict__ Wf, const float* __restrict__ bf_,
    const float* __restrict__ Wi, const float* __restrict__ bi_,
    const float* __restrict__ Wo, const float* __restrict__ bo_,
    const float* __restrict__ Wc, const float* __restrict__ bc_,
    __bf16* __restrict__ xproj)
{
    const int wgM = blockIdx.x;           // 0..255  (64 rows each)
    const int wgN = blockIdx.y;           // 0..15   (128 cols each)
    const int tid = threadIdx.x;
    const int wave = tid >> 6, lane = tid & 63;
    const int mw = wave >> 1, nw = wave & 1;
    const int l15 = lane & 15, lhi = lane >> 4;

    const int gamma = wgN >> 2;           // whole wg in one gate (128 | 512)
    const float* W    = (gamma == 0) ? Wf : (gamma == 1) ? Wi : (gamma == 2) ? Wo : Wc;
    const float* bptr = (gamma == 0) ? bf_ : (gamma == 1) ? bi_ : (gamma == 2) ? bo_ : bc_;

    f32x4 acc[2][4];
#pragma unroll
    for (int m = 0; m < 2; m++)
#pragma unroll
        for (int n = 0; n < 4; n++) acc[m][n] = f32x4{0.f, 0.f, 0.f, 0.f};

    const int rowbase = wgM * 64 + mw * 32;
    const int colbase = wgN * 128 + nw * 64;

#pragma unroll
    for (int kk = 0; kk < 8; ++kk) {
        const int k0 = kk * 32 + lhi * 8;
        bf16x8 a[2], b[4];
#pragma unroll
        for (int m = 0; m < 2; m++) {
            const int r = rowbase + m * 16 + l15;        // x row = b*T + t
            a[m] = f32x8_to_bf16(x + (long)r * Ii + k0);
        }
#pragma unroll
        for (int n = 0; n < 4; n++) {
            const int g = colbase + n * 16 + l15;
            b[n] = f32x8_to_bf16(W + (long)(g & 511) * 768 + k0);
        }
#pragma unroll
        for (int m = 0; m < 2; m++)
#pragma unroll
            for (int n = 0; n < 4; n++)
                acc[m][n] = __builtin_amdgcn_mfma_f32_16x16x32_bf16(a[m], b[n], acc[m][n], 0, 0, 0);
    }

#pragma unroll
    for (int m = 0; m < 2; m++)
#pragma unroll
        for (int n = 0; n < 4; n++) {
            const int g = colbase + n * 16 + l15;
            const float bias = bptr[g & 511];
#pragma unroll
            for (int r = 0; r < 4; r++) {
                const int R = rowbase + m * 16 + lhi * 4 + r;   // = b*T + t
                const int t = R & (Tt - 1), bb = R >> 9;
                xproj[((long)t * Bb + bb) * 2048 + g] = (__bf16)(acc[m][n][r] + bias);
            }
        }
}

// ---------------- recurrence: flag-based barrier, LLC-coherent h exchange ----
__global__ __launch_bounds__(256) void k_rec(
    const float* __restrict__ Wf, const float* __restrict__ Wi,
    const float* __restrict__ Wo, const float* __restrict__ Wc,
    const float* __restrict__ bc0,
    const __bf16* __restrict__ xproj,
    __bf16* __restrict__ hs,           // [2][T][B][H]
    const __bf16* __restrict__ hinit,  // [2][B][H]
    int* flags)                        // [2][32]
{
    const int dir  = blockIdx.x >> 5;
    const int gsel = blockIdx.x & 31;       // owns h-cols [gsel*16, gsel*16+16)
    const int tid  = threadIdx.x;
    const int wave = tid >> 6;              // == gate index (f,i,o,c)
    const int lane = tid & 63;
    const int l15  = lane & 15, lhi = lane >> 4;

    __shared__ __bf16 hlds[32 * 512];       // swizzled h_{t-1}
    __shared__ float  gbuf[32][65];         // recurrent gate contributions

    // persistent B fragments: wave w holds gate w, cols gsel*16..+16 of Wh
    const float* Wp = (wave == 0) ? Wf : (wave == 1) ? Wi : (wave == 2) ? Wo : Wc;
    const float* wrow = Wp + (long)(gsel * 16 + l15) * 768 + Ii;   // recurrent part
    bf16x8 bfrag[16];
#pragma unroll
    for (int kk = 0; kk < 16; ++kk) bfrag[kk] = f32x8_to_bf16(wrow + kk * 32 + lhi * 8);

    // elementwise ownership: adjacent col pair (b_ew, hc0), (b_ew, hc0+1)
    const int b_ew = tid & 31;
    const int hc0  = (tid >> 5) * 2;        // 0,2,..,14
    float c0s = (dir == 0) ? 0.f : bc0[gsel * 16 + hc0];
    float c1s = (dir == 0) ? 0.f : bc0[gsel * 16 + hc0 + 1];

    int* flagd = flags + dir * 32;
    __bf16* hsd = hs + (long)dir * Tt * Bb * Hh;

    // staging geometry: thread owns 16B chunk (r0+4j, ck), j=0..7
    const int ck = tid & 63;                // 16B chunk within row
    const int r0 = tid >> 6;                // base row
    char* lbase = reinterpret_cast<char*>(hlds);

    for (int s = 0; s < Tt; ++s) {
        const int t = (dir == 0) ? s : (Tt - 1 - s);

        // prefetch this step's xproj gates (cached loads, independent of barrier)
        const __bf16* xp = xproj + ((long)t * Bb + b_ew) * 2048;
        float x0[4], x1[4];
#pragma unroll
        for (int g = 0; g < 4; ++g) {
            const unsigned int xv =
                *reinterpret_cast<const unsigned int*>(xp + g * 512 + gsel * 16 + hc0);
            x0[g] = __builtin_bit_cast(float, xv << 16);
            x1[g] = __builtin_bit_cast(float, xv & 0xffff0000u);
        }

        // wave 0 polls all 32 producer flags in parallel (bounded spin)
        if (s > 0 && wave == 0) {
            const int src = lane & 31;
            for (int p = 0; p < 4096; ++p) {
                const int f = __hip_atomic_load(flagd + src, __ATOMIC_RELAXED,
                                                __HIP_MEMORY_SCOPE_AGENT);
                if (__all(f >= s)) break;
                __builtin_amdgcn_s_sleep(2);
            }
        }
        __syncthreads();

        // stage h_{s-1} -> LDS (LLC-coherent loads, 16B XOR swizzle)
        const __bf16* hp = (s == 0) ? (hinit + (long)dir * Bb * Hh)
                                    : (hsd + (long)((dir == 0) ? (t - 1) : (t + 1)) * Bb * Hh);
        const char* gb = reinterpret_cast<const char*>(hp) + r0 * 1024 + ck * 16;
        f32x4 v0, v1, v2, v3, v4, v5, v6, v7;
#define LDC(i, dst) asm volatile("global_load_dwordx4 %0, %1, off sc0 sc1" \
                                 : "=&v"(dst) : "v"(gb + (i) * 4096) : "memory")
        LDC(0, v0); LDC(1, v1); LDC(2, v2); LDC(3, v3);
        LDC(4, v4); LDC(5, v5); LDC(6, v6); LDC(7, v7);
#undef LDC
        asm volatile("s_waitcnt vmcnt(0)" ::: "memory");
        __builtin_amdgcn_sched_barrier(0);
#define STC(i, src) { const int r = r0 + 4 * (i); \
        *reinterpret_cast<f32x4*>(lbase + r * 1024 + ((ck * 16) ^ ((r & 7) << 4))) = src; }
        STC(0, v0); STC(1, v1); STC(2, v2); STC(3, v3);
        STC(4, v4); STC(5, v5); STC(6, v6); STC(7, v7);
#undef STC
        __syncthreads();

        // this wave's gate: [32 x 512] @ [512 x 16]
        f32x4 acc0 = f32x4{0.f, 0.f, 0.f, 0.f};
        f32x4 acc1 = f32x4{0.f, 0.f, 0.f, 0.f};
#pragma unroll
        for (int kk = 0; kk < 16; ++kk) {
            const int kb = kk * 64 + lhi * 16;
            const int rr0 = l15, rr1 = 16 + l15;
            bf16x8 a0 = *reinterpret_cast<const bf16x8*>(
                lbase + rr0 * 1024 + (kb ^ ((rr0 & 7) << 4)));
            bf16x8 a1 = *reinterpret_cast<const bf16x8*>(
                lbase + rr1 * 1024 + (kb ^ ((rr1 & 7) << 4)));
            acc0 = __builtin_amdgcn_mfma_f32_16x16x32_bf16(a0, bfrag[kk], acc0, 0, 0, 0);
            acc1 = __builtin_amdgcn_mfma_f32_16x16x32_bf16(a1, bfrag[kk], acc1, 0, 0, 0);
        }
#pragma unroll
        for (int r = 0; r < 4; ++r) {
            gbuf[lhi * 4 + r][wave * 16 + l15]      = acc0[r];
            gbuf[16 + lhi * 4 + r][wave * 16 + l15] = acc1[r];
        }
        __syncthreads();

        // elementwise LSTM cell for adjacent col pair
        float h0, h1;
        {
            const float gf = x0[0] + gbuf[b_ew][hc0];
            const float gi = x0[1] + gbuf[b_ew][16 + hc0];
            const float go = x0[2] + gbuf[b_ew][32 + hc0];
            const float gc = x0[3] + gbuf[b_ew][48 + hc0];
            const float f  = 1.f / (1.f + __expf(-gf));
            const float ii = 1.f / (1.f + __expf(-gi));
            const float oo = 1.f / (1.f + __expf(-go));
            c0s = f * c0s + ii * tanhf(gc);
            h0 = oo * tanhf(c0s);
        }
        {
            const float gf = x1[0] + gbuf[b_ew][hc0 + 1];
            const float gi = x1[1] + gbuf[b_ew][16 + hc0 + 1];
            const float go = x1[2] + gbuf[b_ew][32 + hc0 + 1];
            const float gc = x1[3] + gbuf[b_ew][48 + hc0 + 1];
            const float f  = 1.f / (1.f + __expf(-gf));
            const float ii = 1.f / (1.f + __expf(-gi));
            const float oo = 1.f / (1.f + __expf(-go));
            c1s = f * c1s + ii * tanhf(gc);
            h1 = oo * tanhf(c1s);
        }
        // pack 2 bf16 -> one dword, write-through to LLC
        const __bf16 b0 = (__bf16)h0, b1 = (__bf16)h1;
        const unsigned int packed =
            ((unsigned int)__builtin_bit_cast(unsigned short, b1) << 16) |
            (unsigned int)__builtin_bit_cast(unsigned short, b0);
        char* dst = reinterpret_cast<char*>(hsd + ((long)t * Bb + b_ew) * Hh + gsel * 16 + hc0);
        asm volatile("global_store_dword %0, %1, off sc0 sc1"
                     :: "v"(dst), "v"(packed) : "memory");
        asm volatile("s_waitcnt vmcnt(0)" ::: "memory");   // h visible at LLC
        __syncthreads();                                    // ...for all waves
        if (tid == 0)
            __hip_atomic_store(flagd + gsel, s + 1, __ATOMIC_RELAXED,
                               __HIP_MEMORY_SCOPE_AGENT);
    }
}

// ---------------- out = cat(hf,hb) @ out_w^T + out_b -> [B][T][O] fp32 -------
__global__ __launch_bounds__(256) void k_out(
    const __bf16* __restrict__ hs,
    const float* __restrict__ out_w,
    const float* __restrict__ out_b,
    float* __restrict__ out)
{
    const int wgM = blockIdx.x;            // 0..255 (64 hs-rows each)
    const int tid = threadIdx.x;
    const int wave = tid >> 6, lane = tid & 63;
    const int mw = wave >> 1, nw = wave & 1;
    const int l15 = lane & 15, lhi = lane >> 4;

    f32x4 acc[2][4];
#pragma unroll
    for (int m = 0; m < 2; m++)
#pragma unroll
        for (int n = 0; n < 4; n++) acc[m][n] = f32x4{0.f, 0.f, 0.f, 0.f};

    const int rowbase = wgM * 64 + mw * 32;   // hs row = t*B + b
    const int colbase = nw * 64;

#pragma unroll 4
    for (int kk = 0; kk < 32; ++kk) {
        const int k0 = kk * 32 + lhi * 8;     // 0..1023
        const int d = k0 >> 9, hk = k0 & 511;
        bf16x8 a[2], b[4];
#pragma unroll
        for (int m = 0; m < 2; m++) {
            const int R = rowbase + m * 16 + l15;
            a[m] = *reinterpret_cast<const bf16x8*>(hs + ((long)d * 16384 + R) * 512 + hk);
        }
#pragma unroll
        for (int n = 0; n < 4; n++) {
            const int o = colbase + n * 16 + l15;
            b[n] = f32x8_to_bf16(out_w + (long)o * 1024 + k0);
        }
#pragma unroll
        for (int m = 0; m < 2; m++)
#pragma unroll
            for (int n = 0; n < 4; n++)
                acc[m][n] = __builtin_amdgcn_mfma_f32_16x16x32_bf16(a[m], b[n], acc[m][n], 0, 0, 0);
    }

#pragma unroll
    for (int m = 0; m < 2; m++)
#pragma unroll
        for (int n = 0; n < 4; n++) {
            const int o = colbase + n * 16 + l15;
            const float bias = out_b[o];
#pragma unroll
            for (int r = 0; r < 4; r++) {
                const int R = rowbase + m * 16 + lhi * 4 + r;   // t*32 + b
                const int tt = R >> 5, bb = R & 31;
                out[((long)bb * Tt + tt) * Oo + o] = acc[m][n][r] + bias;
            }
        }
}

// ---------------- launcher ---------------------------------------------------
extern "C" void kernel_launch(void* const* d_in, const int* in_sizes, int n_in,
                              void* d_out, int out_size, void* d_ws, size_t ws_size,
                              hipStream_t stream) {
    (void)in_sizes; (void)n_in; (void)out_size; (void)ws_size;
    const float* x    = (const float*)d_in[0];
    const float* Wf_w = (const float*)d_in[1];
    const float* Wf_b = (const float*)d_in[2];
    const float* Wi_w = (const float*)d_in[3];
    const float* Wi_b = (const float*)d_in[4];
    const float* Wo_w = (const float*)d_in[5];
    const float* Wo_b = (const float*)d_in[6];
    const float* Wc_w = (const float*)d_in[7];
    const float* Wc_b = (const float*)d_in[8];
    const float* out_w = (const float*)d_in[9];
    const float* out_b = (const float*)d_in[10];
    const float* bh0  = (const float*)d_in[11];
    const float* bc0  = (const float*)d_in[12];

    char* ws = (char*)d_ws;
    __bf16* xproj = (__bf16*)(ws);                       // 67108864 B
    __bf16* hs    = (__bf16*)(ws + 67108864);            // 33554432 B
    __bf16* hinit = (__bf16*)(ws + 100663296);           // 65536 B
    int*    flags = (int*)   (ws + 100728832);           // 256 B

    k_setup<<<64, 256, 0, stream>>>(bh0, hinit, flags);
    dim3 g1(256, 16);
    k_xproj<<<g1, 256, 0, stream>>>(x, Wf_w, Wf_b, Wi_w, Wi_b, Wo_w, Wo_b, Wc_w, Wc_b, xproj);
    k_rec<<<2 * NG, 256, 0, stream>>>(Wf_w, Wi_w, Wo_w, Wc_w, bc0, xproj, hs, hinit, flags);
    k_out<<<256, 256, 0, stream>>>(hs, out_w, out_b, (float*)d_out);
}